// Round 17
// baseline (28.862 us; speedup 1.0000x reference)
//
#include <hip/hip_runtime.h>

namespace {
constexpr int kB = 32, kT = 30, kD = 512, kL = 196;
constexpr float kK = 2.8853900817779268f;  // 2*log2(e)
constexpr size_t kGsz = (size_t)kB * kT * kL;  // 188,160
constexpr int kNP = 16;                        // partials (32-d slices)

// vwi/u + vwj/v = (vwi*v + vwj*u) * rcp(u*v): 1 rcp per 2 elements
#define PAIR(ex, ey, fx, fy, vx, vy, acc)                                   \
  {                                                                         \
    const float u_ = fmaf(ex, fx, 1.f);                                     \
    const float v_ = fmaf(ey, fy, 1.f);                                     \
    acc = fmaf(fmaf(v_, vx, u_ * vy), __builtin_amdgcn_rcpf(u_ * v_), acc); \
  }

// g16[dqs][b][t][l] (l<192) = sum over 32 d of vw_d/(1+E*F).
// 512 blocks (bg:8 XCD-affine x bi:4 x dqs:16) x 512 thr (8 waves).
// Waves = (tg:4 x dh:2); wave = 8t x 192l x 16d; lane owns l,l+64,l+128.
// Per c4-step: 8 E + 3 F + 1 vw = 12 LDS reads per 6144 elements.
__global__ __launch_bounds__(512) void k_score(const float* __restrict__ x,
                                               const float* __restrict__ w,
                                               const float* __restrict__ img,
                                               const float* __restrict__ vw,
                                               float* __restrict__ g16) {
  __shared__ __align__(16) float4 Fl4[8 * 192];  // [c4][l swz]  24 KB
  __shared__ __align__(16) float4 El4[32 * 8];   // [row][c4]     4 KB
  __shared__ __align__(16) float4 vwl4[8];
  __shared__ float sc[4 * 8 * 192];              // dh-merge     24 KB
  int n = blockIdx.x;
  const int bg = n & 7;
  const int m = n >> 3;  // 64 = 4 bi * 16 dqs
  const int bi = m & 3;
  const int dqs = m >> 2;
  const int b = bg * 4 + bi;
  const int d0 = dqs * 32;
  const int tid = threadIdx.x;
  // stage F = 2^(kK*img): 1536 f4; 8 threads/row -> 128B contiguous reads;
  // write swizzled: low-3 bits of l XOR'd with c4 (bijective per c4).
#pragma unroll
  for (int k = 0; k < 3; ++k) {
    const int i = tid + k * 512;
    const int l = i >> 3, c4 = i & 7;
    const float4 v =
        *(const float4*)(img + ((size_t)(b * kL + l)) * kD + d0 + 4 * c4);
    float4 o;
    o.x = __builtin_amdgcn_exp2f(kK * v.x);
    o.y = __builtin_amdgcn_exp2f(kK * v.y);
    o.z = __builtin_amdgcn_exp2f(kK * v.z);
    o.w = __builtin_amdgcn_exp2f(kK * v.w);
    Fl4[c4 * 192 + ((l & ~7) | ((l ^ c4) & 7))] = o;
  }
  // stage E = 2^(kK*(x+w)) rows 0..31 (30,31 clamp to 29; never stored)
  if (tid < 256) {
    const int row = tid >> 3, c4 = tid & 7;
    const int tc = (row < kT) ? row : kT - 1;
    const size_t gi = ((size_t)(b * kT + tc)) * kD + d0 + 4 * c4;
    const float4 xv = *(const float4*)(x + gi);
    const float4 wv4 = *(const float4*)(w + gi);
    float4 e;
    e.x = __builtin_amdgcn_exp2f(kK * (xv.x + wv4.x));
    e.y = __builtin_amdgcn_exp2f(kK * (xv.y + wv4.y));
    e.z = __builtin_amdgcn_exp2f(kK * (xv.z + wv4.z));
    e.w = __builtin_amdgcn_exp2f(kK * (xv.w + wv4.w));
    El4[row * 8 + c4] = e;
  }
  if (tid < 8) vwl4[tid] = *(const float4*)(vw + d0 + 4 * tid);
  __syncthreads();
  const int lane = tid & 63, wva = tid >> 6;
  const int tg = wva & 3, dh = wva >> 2;  // t-group of 8, d-half of 16
  const int r0 = tg * 8;
  float acc[8][3];
#pragma unroll
  for (int tt = 0; tt < 8; ++tt)
#pragma unroll
    for (int j = 0; j < 3; ++j) acc[tt][j] = 0.f;
#pragma unroll
  for (int s = 0; s < 4; ++s) {
    const int c4 = dh * 4 + s;
    const float4 vv = vwl4[c4];  // uniform broadcast
    const int sw = (lane ^ c4) & 7;
    const int bse = (lane & 56) + sw;
    float4 f[3];
#pragma unroll
    for (int j = 0; j < 3; ++j) f[j] = Fl4[c4 * 192 + bse + 64 * j];
#pragma unroll
    for (int tt = 0; tt < 8; ++tt) {
      const float4 E = El4[(r0 + tt) * 8 + c4];  // uniform broadcast
#pragma unroll
      for (int j = 0; j < 3; ++j) {
        PAIR(E.x, E.y, f[j].x, f[j].y, vv.x, vv.y, acc[tt][j]);
        PAIR(E.z, E.w, f[j].z, f[j].w, vv.z, vv.w, acc[tt][j]);
      }
    }
  }
  // merge the two d-halves: dh=1 -> scratch; dh=0 adds and stores
  if (dh == 1) {
#pragma unroll
    for (int tt = 0; tt < 8; ++tt)
#pragma unroll
      for (int j = 0; j < 3; ++j)
        sc[(r0 + tt) * 192 + lane + 64 * j] = acc[tt][j];
  }
  __syncthreads();
  if (dh == 0) {
    float* gp = g16 + (size_t)dqs * kGsz + ((size_t)(b * kT + r0)) * kL + lane;
#pragma unroll
    for (int tt = 0; tt < 8; ++tt) {
      if (r0 + tt < kT) {
#pragma unroll
        for (int j = 0; j < 3; ++j) {
          gp[(size_t)tt * kL + 64 * j] =
              acc[tt][j] + sc[(r0 + tt) * 192 + lane + 64 * j];
        }
      }
    }
  }
}

// Fused softmax + context, dedup'd. 192 blocks (bg:8 x bi:4 x tgc:6) x 512.
// Phase 1: waves 0-4 each compute ONE softmax row (t = t0+wv) -> AL2[wv][l];
//   tail l=192..195 inline; sums 16 partials. 960 rows / 960 waves (no dup).
// Phase 2: 8 waves = (lq:4 l-quarters x dh:2 d-halves), 4-deep img dbuf;
//   two-stage reduction through red[8][5][256].
__global__ __launch_bounds__(512) void k_ctxa(const float* __restrict__ g16,
                                              const float* __restrict__ x,
                                              const float* __restrict__ w,
                                              const float* __restrict__ img,
                                              const float* __restrict__ vw,
                                              float* __restrict__ out) {
  __shared__ float AL2[5][200];                   // 4 KB
  __shared__ __align__(16) float red[8][5][256];  // 40 KB
  int n = blockIdx.x;
  const int bg = n & 7;
  const int m = n >> 3;  // 24 = 4 bi * 6 tgc
  const int bi = m & 3;
  const int tgc = m >> 2;
  const int b = bg * 4 + bi;
  const int t0 = tgc * 5;
  const int tid = threadIdx.x;
  const int lane = tid & 63;
  const int wv = tid >> 6;
  // ---- phase 1: one softmax row per wave (waves 0..4) ----
  if (wv < 5) {
    const int t = t0 + wv;  // <= 29 always
    const int l4 = lane & 3, dc = lane >> 2;
    const float* ir = img + ((size_t)(b * kL + 192 + l4)) * kD + dc * 32;
    const float* xr = x + ((size_t)(b * kT + t)) * kD + dc * 32;
    const float* wr = w + ((size_t)(b * kT + t)) * kD + dc * 32;
    const float* vr = vw + dc * 32;
    float tgv = 0.f;
#pragma unroll
    for (int k = 0; k < 8; ++k) {
      const float4 iv = *(const float4*)(ir + 4 * k);
      const float4 xv = *(const float4*)(xr + 4 * k);
      const float4 wv4 = *(const float4*)(wr + 4 * k);
      const float4 vv = *(const float4*)(vr + 4 * k);
      const float fx = __builtin_amdgcn_exp2f(kK * iv.x);
      const float fy = __builtin_amdgcn_exp2f(kK * iv.y);
      const float fz = __builtin_amdgcn_exp2f(kK * iv.z);
      const float fw = __builtin_amdgcn_exp2f(kK * iv.w);
      const float ex = __builtin_amdgcn_exp2f(kK * (xv.x + wv4.x));
      const float ey = __builtin_amdgcn_exp2f(kK * (xv.y + wv4.y));
      const float ez = __builtin_amdgcn_exp2f(kK * (xv.z + wv4.z));
      const float ew = __builtin_amdgcn_exp2f(kK * (xv.w + wv4.w));
      PAIR(ex, ey, fx, fy, vv.x, vv.y, tgv);
      PAIR(ez, ew, fz, fw, vv.z, vv.w, tgv);
    }
#pragma unroll
    for (int mm = 4; mm < 64; mm <<= 1) tgv += __shfl_xor(tgv, mm, 64);
    const size_t base = ((size_t)(b * kT + t)) * kL;
    float q0 = 0.f, q1 = 0.f, q2 = 0.f;
#pragma unroll
    for (int p = 0; p < kNP; ++p) {
      const float* gp = g16 + (size_t)p * kGsz + base;
      q0 += gp[lane];
      q1 += gp[lane + 64];
      q2 += gp[lane + 128];
    }
    q0 *= kK; q1 *= kK; q2 *= kK;
    float q3 = (lane < 4) ? tgv * kK : __builtin_inff();
    float mn = fminf(fminf(q0, q1), fminf(q2, q3));
#pragma unroll
    for (int mm = 1; mm < 64; mm <<= 1) mn = fminf(mn, __shfl_xor(mn, mm, 64));
    const float e0 = __builtin_amdgcn_exp2f(mn - q0);
    const float e1 = __builtin_amdgcn_exp2f(mn - q1);
    const float e2 = __builtin_amdgcn_exp2f(mn - q2);
    const float e3 = (lane < 4) ? __builtin_amdgcn_exp2f(mn - q3) : 0.f;
    float s = e0 + e1 + e2 + e3;
#pragma unroll
    for (int mm = 1; mm < 64; mm <<= 1) s += __shfl_xor(s, mm, 64);
    const float rs = __builtin_amdgcn_rcpf(s);
    AL2[wv][lane] = e0 * rs;
    AL2[wv][lane + 64] = e1 * rs;
    AL2[wv][lane + 128] = e2 * rs;
    if (lane < 4) AL2[wv][lane + 192] = e3 * rs;
  }
  __syncthreads();
  // ---- phase 2: context GEMV; wave = (lq l-quarter, dh d-half) ----
  const int lq = __builtin_amdgcn_readfirstlane(wv & 3);
  const int dh = __builtin_amdgcn_readfirstlane(wv >> 2);
  const int d0 = dh * 256;
  const int lb = lq * 49;
  const float* ip = img + ((size_t)(b * kL + lb)) * kD + d0 + 4 * lane;
  float4 acc[5];
#pragma unroll
  for (int j = 0; j < 5; ++j) acc[j] = {0.f, 0.f, 0.f, 0.f};
  auto loadI = [&](float4* dst, int bb) {
#pragma unroll
    for (int j = 0; j < 4; ++j)
      dst[j] = *(const float4*)(ip + (size_t)(bb * 4 + j) * kD);
  };
  auto compI = [&](const float4* f, int bb) {
#pragma unroll
    for (int j = 0; j < 4; ++j) {
      const int l = lb + bb * 4 + j;
      const float a0 = AL2[0][l];  // uniform broadcasts
      const float a1 = AL2[1][l];
      const float a2 = AL2[2][l];
      const float a3 = AL2[3][l];
      const float a4 = AL2[4][l];
      acc[0].x = fmaf(f[j].x, a0, acc[0].x); acc[0].y = fmaf(f[j].y, a0, acc[0].y);
      acc[0].z = fmaf(f[j].z, a0, acc[0].z); acc[0].w = fmaf(f[j].w, a0, acc[0].w);
      acc[1].x = fmaf(f[j].x, a1, acc[1].x); acc[1].y = fmaf(f[j].y, a1, acc[1].y);
      acc[1].z = fmaf(f[j].z, a1, acc[1].z); acc[1].w = fmaf(f[j].w, a1, acc[1].w);
      acc[2].x = fmaf(f[j].x, a2, acc[2].x); acc[2].y = fmaf(f[j].y, a2, acc[2].y);
      acc[2].z = fmaf(f[j].z, a2, acc[2].z); acc[2].w = fmaf(f[j].w, a2, acc[2].w);
      acc[3].x = fmaf(f[j].x, a3, acc[3].x); acc[3].y = fmaf(f[j].y, a3, acc[3].y);
      acc[3].z = fmaf(f[j].z, a3, acc[3].z); acc[3].w = fmaf(f[j].w, a3, acc[3].w);
      acc[4].x = fmaf(f[j].x, a4, acc[4].x); acc[4].y = fmaf(f[j].y, a4, acc[4].y);
      acc[4].z = fmaf(f[j].z, a4, acc[4].z); acc[4].w = fmaf(f[j].w, a4, acc[4].w);
    }
  };
  float4 fA[4], fB[4];
  loadI(fA, 0);
#pragma unroll
  for (int bb = 0; bb < 12; ++bb) {
    if (bb + 1 < 12) {
      if ((bb + 1) & 1) loadI(fB, bb + 1);
      else loadI(fA, bb + 1);
    }
    if (bb & 1) compI(fB, bb);
    else compI(fA, bb);
  }
  {  // tail l-index 48 of this quarter
    const float4 v = *(const float4*)(ip + (size_t)48 * kD);
    const int l = lb + 48;
    const float a0 = AL2[0][l], a1 = AL2[1][l], a2 = AL2[2][l],
                a3 = AL2[3][l], a4 = AL2[4][l];
    acc[0].x = fmaf(v.x, a0, acc[0].x); acc[0].y = fmaf(v.y, a0, acc[0].y);
    acc[0].z = fmaf(v.z, a0, acc[0].z); acc[0].w = fmaf(v.w, a0, acc[0].w);
    acc[1].x = fmaf(v.x, a1, acc[1].x); acc[1].y = fmaf(v.y, a1, acc[1].y);
    acc[1].z = fmaf(v.z, a1, acc[1].z); acc[1].w = fmaf(v.w, a1, acc[1].w);
    acc[2].x = fmaf(v.x, a2, acc[2].x); acc[2].y = fmaf(v.y, a2, acc[2].y);
    acc[2].z = fmaf(v.z, a2, acc[2].z); acc[2].w = fmaf(v.w, a2, acc[2].w);
    acc[3].x = fmaf(v.x, a3, acc[3].x); acc[3].y = fmaf(v.y, a3, acc[3].y);
    acc[3].z = fmaf(v.z, a3, acc[3].z); acc[3].w = fmaf(v.w, a3, acc[3].w);
    acc[4].x = fmaf(v.x, a4, acc[4].x); acc[4].y = fmaf(v.y, a4, acc[4].y);
    acc[4].z = fmaf(v.z, a4, acc[4].z); acc[4].w = fmaf(v.w, a4, acc[4].w);
  }
#pragma unroll
  for (int j = 0; j < 5; ++j) *(float4*)&red[wv][j][4 * lane] = acc[j];
  __syncthreads();
  // two-stage reduce: threads = (dhh:2 x col:256); sum 4 l-quarters
  const int col = tid & 255, dhh = tid >> 8;
#pragma unroll
  for (int j = 0; j < 5; ++j) {
    const float s = red[dhh * 4 + 0][j][col] + red[dhh * 4 + 1][j][col] +
                    red[dhh * 4 + 2][j][col] + red[dhh * 4 + 3][j][col];
    out[((size_t)(b * kT + t0 + j)) * kD + dhh * 256 + col] = s;
  }
}
}  // namespace

extern "C" void kernel_launch(void* const* d_in, const int* in_sizes, int n_in,
                              void* d_out, int out_size, void* d_ws, size_t ws_size,
                              hipStream_t stream) {
  const float* x = (const float*)d_in[0];
  const float* wordemb = (const float*)d_in[1];
  const float* img = (const float*)d_in[2];
  const float* vw = (const float*)d_in[3];
  // v_b (d_in[4]) cancels in the softmax along with sum(v_w) — unused by design.
  float* out = (float*)d_out;
  float* g16 = (float*)d_ws;  // 16 * 188,160 floats = 12.04 MB
  hipLaunchKernelGGL(k_score, dim3(512), dim3(512), 0, stream, x, wordemb, img,
                     vw, g16);
  hipLaunchKernelGGL(k_ctxa, dim3(192), dim3(512), 0, stream, g16, x, wordemb,
                     img, vw, out);
}